// Round 1
// baseline (556.986 us; speedup 1.0000x reference)
//
#include <hip/hip_runtime.h>
#include <math.h>

// ---------------------------------------------------------------------------
// GCN: 3 layers (128->32->32->32), CSR-by-dst aggregation, readout + MLP head
// ---------------------------------------------------------------------------

__global__ void k_count(const int* __restrict__ dst, int* __restrict__ cnt, int E) {
    int e = blockIdx.x * blockDim.x + threadIdx.x;
    if (e < E) atomicAdd(&cnt[dst[e]], 1);
}

__global__ void k_dis(const int* __restrict__ cnt, float* __restrict__ dis,
                      float* __restrict__ selfc, int n) {
    int i = blockIdx.x * blockDim.x + threadIdx.x;
    if (i < n) {
        float d = 1.0f + (float)cnt[i];
        dis[i]   = 1.0f / sqrtf(d);
        selfc[i] = 1.0f / d;
    }
}

// inclusive block scan of cnt -> rowptr[i+1] (without inter-block offsets), partials[b]=block sum
__global__ void k_scan1(const int* __restrict__ cnt, int* __restrict__ rowptr,
                        int* __restrict__ partials, int n) {
    __shared__ int s[256];
    int i = blockIdx.x * 256 + threadIdx.x;
    int v = (i < n) ? cnt[i] : 0;
    s[threadIdx.x] = v;
    __syncthreads();
    for (int off = 1; off < 256; off <<= 1) {
        int t = (threadIdx.x >= off) ? s[threadIdx.x - off] : 0;
        __syncthreads();
        s[threadIdx.x] += t;
        __syncthreads();
    }
    if (i < n) rowptr[i + 1] = s[threadIdx.x];
    if (threadIdx.x == 255) partials[blockIdx.x] = s[255];
}

// exclusive scan of partials (nb <= 512), single block
__global__ void k_scan2(int* __restrict__ partials, int nb) {
    __shared__ int s[512];
    int t = threadIdx.x;
    s[t] = (t < nb) ? partials[t] : 0;
    __syncthreads();
    for (int off = 1; off < 512; off <<= 1) {
        int v = (t >= off) ? s[t - off] : 0;
        __syncthreads();
        s[t] += v;
        __syncthreads();
    }
    if (t < nb) partials[t] = (t == 0) ? 0 : s[t - 1];
}

__global__ void k_scan3(int* __restrict__ rowptr, const int* __restrict__ partials, int n) {
    int i = blockIdx.x * 256 + threadIdx.x;
    if (i < n) rowptr[i + 1] += partials[blockIdx.x];
    if (i == 0) rowptr[0] = 0;
}

__global__ void k_fill(const int* __restrict__ src, const int* __restrict__ dst,
                       const float* __restrict__ dis, const int* __restrict__ rowptr,
                       int* __restrict__ cursor, int* __restrict__ csr_src,
                       float* __restrict__ csr_coef, int E) {
    int e = blockIdx.x * blockDim.x + threadIdx.x;
    if (e >= E) return;
    int d = dst[e], s = src[e];
    int pos = rowptr[d] + atomicAdd(&cursor[d], 1);
    csr_src[pos]  = s;
    csr_coef[pos] = dis[s] * dis[d];
}

// hp[n,32] = h[n, ldh(first K cols)] @ W[K,32]   (8 rows per 256-thread block)
template <int K>
__global__ void k_gemm(const float* __restrict__ h, int ldh, const float* __restrict__ W,
                       float* __restrict__ hp, int n) {
    __shared__ float sW[K * 32];
    __shared__ float sh[8][K + 1];
    int tid = threadIdx.x;
    for (int i = tid; i < K * 32; i += 256) sW[i] = W[i];
    int row0 = blockIdx.x * 8;
    for (int idx = tid; idx < 8 * K; idx += 256) {
        int r = idx / K, c = idx % K;
        sh[r][c] = (row0 + r < n) ? h[(size_t)(row0 + r) * ldh + c] : 0.0f;
    }
    __syncthreads();
    int r = tid >> 5, col = tid & 31;
    float acc = 0.0f;
#pragma unroll 8
    for (int k = 0; k < K; ++k) acc += sh[r][k] * sW[k * 32 + col];
    if (row0 + r < n) hp[(size_t)(row0 + r) * 32 + col] = acc;
}

// out[node, ldo cols at given offset] = tanh( sum_in-edges coef*hp[src] + hp[node]*selfc + b )
__global__ void k_agg(const float* __restrict__ hp, const int* __restrict__ rowptr,
                      const int* __restrict__ csr_src, const float* __restrict__ csr_coef,
                      const float* __restrict__ selfc, const float* __restrict__ bias,
                      float* __restrict__ out, int ldo, int n) {
    int g    = (blockIdx.x * blockDim.x + threadIdx.x) >> 5;
    int lane = threadIdx.x & 31;
    if (g >= n) return;
    float acc = 0.0f;
    int e0 = rowptr[g], e1 = rowptr[g + 1];
    for (int e = e0; e < e1; ++e) {
        int s = csr_src[e];
        acc += csr_coef[e] * hp[(size_t)s * 32 + lane];
    }
    float v = acc + hp[(size_t)g * 32 + lane] * selfc[g] + bias[lane];
    out[(size_t)g * ldo + lane] = tanhf(v);
}

__global__ void k_idx(const int* __restrict__ batch, int* __restrict__ idx, int n, int g) {
    int i = blockIdx.x * blockDim.x + threadIdx.x;
    if (i >= g) return;
    int lo = 0, hi = n;
    while (lo < hi) {
        int mid = (lo + hi) >> 1;
        if (batch[mid] < i) lo = mid + 1; else hi = mid;
    }
    idx[i] = lo;
}

// per graph: gv[96] -> hidden[128] (relu) -> logits[2] -> log_softmax
__global__ void k_head(const float* __restrict__ cat, const int* __restrict__ idx,
                       const float* __restrict__ w1, const float* __restrict__ b1,
                       const float* __restrict__ w2, const float* __restrict__ b2,
                       float* __restrict__ out) {
    __shared__ float gv[96];
    __shared__ float s0[128];
    __shared__ float s1[128];
    int g = blockIdx.x, t = threadIdx.x;
    int node = idx[g];
    if (t < 96) gv[t] = cat[(size_t)node * 96 + t];
    __syncthreads();
    float acc = b1[t];
#pragma unroll 8
    for (int i = 0; i < 96; ++i) acc += gv[i] * w1[i * 128 + t];
    float h = fmaxf(acc, 0.0f);
    s0[t] = h * w2[t * 2 + 0];
    s1[t] = h * w2[t * 2 + 1];
    __syncthreads();
    for (int off = 64; off > 0; off >>= 1) {
        if (t < off) { s0[t] += s0[t + off]; s1[t] += s1[t + off]; }
        __syncthreads();
    }
    if (t == 0) {
        float l0 = s0[0] + b2[0];
        float l1 = s1[0] + b2[1];
        float m  = fmaxf(l0, l1);
        float lse = m + logf(expf(l0 - m) + expf(l1 - m));
        out[(size_t)g * 2 + 0] = l0 - lse;
        out[(size_t)g * 2 + 1] = l1 - lse;
    }
}

extern "C" void kernel_launch(void* const* d_in, const int* in_sizes, int n_in,
                              void* d_out, int out_size, void* d_ws, size_t ws_size,
                              hipStream_t stream) {
    const float* x    = (const float*)d_in[0];
    const int*   ei   = (const int*)d_in[1];
    const int*   batch= (const int*)d_in[2];
    // d_in[3] = num_graphs (device scalar) - derived from out_size instead
    const float* W1   = (const float*)d_in[4];
    const float* b1   = (const float*)d_in[5];
    const float* W2   = (const float*)d_in[6];
    const float* b2   = (const float*)d_in[7];
    const float* W3   = (const float*)d_in[8];
    const float* b3   = (const float*)d_in[9];
    const float* l1w  = (const float*)d_in[10];
    const float* l1b  = (const float*)d_in[11];
    const float* l2w  = (const float*)d_in[12];
    const float* l2b  = (const float*)d_in[13];
    float* out = (float*)d_out;

    const int N = in_sizes[0] / 128;
    const int E = in_sizes[1] / 2;
    const int G = out_size / 2;
    const int* src = ei;
    const int* dst = ei + E;

    char* w = (char*)d_ws;
    auto alloc = [&](size_t bytes) {
        char* p = w;
        w += (bytes + 255) & ~(size_t)255;
        return p;
    };
    int*   cnt      = (int*)  alloc((size_t)N * 4);
    float* dis      = (float*)alloc((size_t)N * 4);
    float* selfc    = (float*)alloc((size_t)N * 4);
    int*   rowptr   = (int*)  alloc((size_t)(N + 1) * 4);
    int*   cursor   = (int*)  alloc((size_t)N * 4);
    int*   partials = (int*)  alloc(((size_t)(N + 255) / 256) * 4);
    int*   csr_src  = (int*)  alloc((size_t)E * 4);
    float* csr_coef = (float*)alloc((size_t)E * 4);
    float* hp       = (float*)alloc((size_t)N * 32 * 4);
    float* catb     = (float*)alloc((size_t)N * 96 * 4);
    int*   idx      = (int*)  alloc((size_t)G * 4);

    const int nb  = (N + 255) / 256;   // scan blocks
    const int ebl = (E + 255) / 256;
    const int nodes_bl = (N * 32 + 255) / 256;   // 8 nodes per block
    const int gemm_bl  = (N + 7) / 8;

    hipMemsetAsync(cnt,    0, (size_t)N * 4, stream);
    hipMemsetAsync(cursor, 0, (size_t)N * 4, stream);

    k_count<<<ebl, 256, 0, stream>>>(dst, cnt, E);
    k_dis<<<nb, 256, 0, stream>>>(cnt, dis, selfc, N);
    k_scan1<<<nb, 256, 0, stream>>>(cnt, rowptr, partials, N);
    k_scan2<<<1, 512, 0, stream>>>(partials, nb);
    k_scan3<<<nb, 256, 0, stream>>>(rowptr, partials, N);
    k_fill<<<ebl, 256, 0, stream>>>(src, dst, dis, rowptr, cursor, csr_src, csr_coef, E);

    // layer 1: x[ N,128 ] @ W1 -> hp ; aggregate -> catb[:,0:32]
    k_gemm<128><<<gemm_bl, 256, 0, stream>>>(x, 128, W1, hp, N);
    k_agg<<<nodes_bl, 256, 0, stream>>>(hp, rowptr, csr_src, csr_coef, selfc, b1, catb + 0, 96, N);
    // layer 2: catb[:,0:32] @ W2 -> hp ; aggregate -> catb[:,32:64]
    k_gemm<32><<<gemm_bl, 256, 0, stream>>>(catb + 0, 96, W2, hp, N);
    k_agg<<<nodes_bl, 256, 0, stream>>>(hp, rowptr, csr_src, csr_coef, selfc, b2, catb + 32, 96, N);
    // layer 3: catb[:,32:64] @ W3 -> hp ; aggregate -> catb[:,64:96]
    k_gemm<32><<<gemm_bl, 256, 0, stream>>>(catb + 32, 96, W3, hp, N);
    k_agg<<<nodes_bl, 256, 0, stream>>>(hp, rowptr, csr_src, csr_coef, selfc, b3, catb + 64, 96, N);

    k_idx<<<(G + 255) / 256, 256, 0, stream>>>(batch, idx, N, G);
    k_head<<<G, 128, 0, stream>>>(catb, idx, l1w, l1b, l2w, l2b, out);
}

// Round 2
// 500.718 us; speedup vs baseline: 1.1124x; 1.1124x over previous
//
#include <hip/hip_runtime.h>
#include <math.h>

// ---------------------------------------------------------------------------
// GCN: 3 layers (128->32->32->32), CSR-by-dst aggregation, readout + MLP head
// Algebra: agg[g] = tanh( dis[g] * ( sum_{e:dst=g} hps[src_e] + hps[g] ) + b )
//          where hps = dis ⊙ (h @ W)   (so no per-edge coef storage needed)
// ---------------------------------------------------------------------------

__global__ void k_count(const int* __restrict__ dst, int* __restrict__ cnt, int E) {
    int e = blockIdx.x * blockDim.x + threadIdx.x;
    if (e < E) atomicAdd(&cnt[dst[e]], 1);
}

__global__ void k_dis(const int* __restrict__ cnt, float* __restrict__ dis, int n) {
    int i = blockIdx.x * blockDim.x + threadIdx.x;
    if (i < n) {
        float d = 1.0f + (float)cnt[i];
        dis[i] = 1.0f / sqrtf(d);
    }
}

// inclusive block scan of cnt -> rowptr[i+1] (without inter-block offsets), partials[b]=block sum
__global__ void k_scan1(const int* __restrict__ cnt, int* __restrict__ rowptr,
                        int* __restrict__ partials, int n) {
    __shared__ int s[256];
    int i = blockIdx.x * 256 + threadIdx.x;
    int v = (i < n) ? cnt[i] : 0;
    s[threadIdx.x] = v;
    __syncthreads();
    for (int off = 1; off < 256; off <<= 1) {
        int t = (threadIdx.x >= off) ? s[threadIdx.x - off] : 0;
        __syncthreads();
        s[threadIdx.x] += t;
        __syncthreads();
    }
    if (i < n) rowptr[i + 1] = s[threadIdx.x];
    if (threadIdx.x == 255) partials[blockIdx.x] = s[255];
}

// exclusive scan of partials (nb <= 512), single block
__global__ void k_scan2(int* __restrict__ partials, int nb) {
    __shared__ int s[512];
    int t = threadIdx.x;
    s[t] = (t < nb) ? partials[t] : 0;
    __syncthreads();
    for (int off = 1; off < 512; off <<= 1) {
        int v = (t >= off) ? s[t - off] : 0;
        __syncthreads();
        s[t] += v;
        __syncthreads();
    }
    if (t < nb) partials[t] = (t == 0) ? 0 : s[t - 1];
}

__global__ void k_scan3(int* __restrict__ rowptr, const int* __restrict__ partials, int n) {
    int i = blockIdx.x * 256 + threadIdx.x;
    if (i < n) rowptr[i + 1] += partials[blockIdx.x];
    if (i == 0) rowptr[0] = 0;
}

// cursor pre-initialized to rowptr[0..N-1]; one atomic gives the slot directly.
__global__ void k_fill(const int* __restrict__ src, const int* __restrict__ dst,
                       int* __restrict__ cursor, int* __restrict__ csr_src, int E) {
    int e = blockIdx.x * blockDim.x + threadIdx.x;
    if (e >= E) return;
    int d = dst[e], s = src[e];
    int pos = atomicAdd(&cursor[d], 1);
    __builtin_nontemporal_store(s, &csr_src[pos]);
}

// hps[n,32] = dis[row] * ( h[n, first K cols of ldh] @ W[K,32] )
template <int K>
__global__ void k_gemm(const float* __restrict__ h, int ldh, const float* __restrict__ W,
                       const float* __restrict__ dis, float* __restrict__ hps, int n) {
    __shared__ float sW[K * 32];
    __shared__ float sh[8][K + 1];
    int tid = threadIdx.x;
    for (int i = tid; i < K * 32; i += 256) sW[i] = W[i];
    int row0 = blockIdx.x * 8;
    for (int idx = tid; idx < 8 * K; idx += 256) {
        int r = idx / K, c = idx % K;
        sh[r][c] = (row0 + r < n) ? h[(size_t)(row0 + r) * ldh + c] : 0.0f;
    }
    __syncthreads();
    int r = tid >> 5, col = tid & 31;
    float acc = 0.0f;
#pragma unroll 8
    for (int k = 0; k < K; ++k) acc += sh[r][k] * sW[k * 32 + col];
    int row = row0 + r;
    if (row < n) hps[(size_t)row * 32 + col] = acc * dis[row];
}

// out[node, col+offset] = tanh( dis[g] * (sum_in-edges hps[src] + hps[g]) + b )
__global__ void k_agg(const float* __restrict__ hps, const int* __restrict__ rowptr,
                      const int* __restrict__ csr_src, const float* __restrict__ dis,
                      const float* __restrict__ bias, float* __restrict__ out,
                      int ldo, int n) {
    int g    = (blockIdx.x * blockDim.x + threadIdx.x) >> 5;
    int lane = threadIdx.x & 31;
    if (g >= n) return;
    float acc = hps[(size_t)g * 32 + lane];   // self term (dis[g]^2 * h' = dis*hps)
    int e0 = rowptr[g], e1 = rowptr[g + 1];
    int e = e0;
    for (; e + 1 < e1; e += 2) {
        int s0 = csr_src[e];
        int s1 = csr_src[e + 1];
        float v0 = hps[(size_t)s0 * 32 + lane];
        float v1 = hps[(size_t)s1 * 32 + lane];
        acc += v0 + v1;
    }
    if (e < e1) acc += hps[(size_t)csr_src[e] * 32 + lane];
    float v = dis[g] * acc + bias[lane];
    out[(size_t)g * ldo + lane] = tanhf(v);
}

__global__ void k_idx(const int* __restrict__ batch, int* __restrict__ idx, int n, int g) {
    int i = blockIdx.x * blockDim.x + threadIdx.x;
    if (i >= g) return;
    int lo = 0, hi = n;
    while (lo < hi) {
        int mid = (lo + hi) >> 1;
        if (batch[mid] < i) lo = mid + 1; else hi = mid;
    }
    idx[i] = lo;
}

// per graph: gv[96] -> hidden[128] (relu) -> logits[2] -> log_softmax
__global__ void k_head(const float* __restrict__ cat, const int* __restrict__ idx,
                       const float* __restrict__ w1, const float* __restrict__ b1,
                       const float* __restrict__ w2, const float* __restrict__ b2,
                       float* __restrict__ out) {
    __shared__ float gv[96];
    __shared__ float s0[128];
    __shared__ float s1[128];
    int g = blockIdx.x, t = threadIdx.x;
    int node = idx[g];
    if (t < 96) gv[t] = cat[(size_t)node * 96 + t];
    __syncthreads();
    float acc = b1[t];
#pragma unroll 8
    for (int i = 0; i < 96; ++i) acc += gv[i] * w1[i * 128 + t];
    float h = fmaxf(acc, 0.0f);
    s0[t] = h * w2[t * 2 + 0];
    s1[t] = h * w2[t * 2 + 1];
    __syncthreads();
    for (int off = 64; off > 0; off >>= 1) {
        if (t < off) { s0[t] += s0[t + off]; s1[t] += s1[t + off]; }
        __syncthreads();
    }
    if (t == 0) {
        float l0 = s0[0] + b2[0];
        float l1 = s1[0] + b2[1];
        float m  = fmaxf(l0, l1);
        float lse = m + logf(expf(l0 - m) + expf(l1 - m));
        out[(size_t)g * 2 + 0] = l0 - lse;
        out[(size_t)g * 2 + 1] = l1 - lse;
    }
}

extern "C" void kernel_launch(void* const* d_in, const int* in_sizes, int n_in,
                              void* d_out, int out_size, void* d_ws, size_t ws_size,
                              hipStream_t stream) {
    const float* x    = (const float*)d_in[0];
    const int*   ei   = (const int*)d_in[1];
    const int*   batch= (const int*)d_in[2];
    const float* W1   = (const float*)d_in[4];
    const float* b1   = (const float*)d_in[5];
    const float* W2   = (const float*)d_in[6];
    const float* b2   = (const float*)d_in[7];
    const float* W3   = (const float*)d_in[8];
    const float* b3   = (const float*)d_in[9];
    const float* l1w  = (const float*)d_in[10];
    const float* l1b  = (const float*)d_in[11];
    const float* l2w  = (const float*)d_in[12];
    const float* l2b  = (const float*)d_in[13];
    float* out = (float*)d_out;

    const int N = in_sizes[0] / 128;
    const int E = in_sizes[1] / 2;
    const int G = out_size / 2;
    const int* src = ei;
    const int* dst = ei + E;

    char* w = (char*)d_ws;
    auto alloc = [&](size_t bytes) {
        char* p = w;
        w += (bytes + 255) & ~(size_t)255;
        return p;
    };
    int*   cnt      = (int*)  alloc((size_t)N * 4);
    float* dis      = (float*)alloc((size_t)N * 4);
    int*   rowptr   = (int*)  alloc((size_t)(N + 1) * 4);
    int*   cursor   = (int*)  alloc((size_t)N * 4);
    int*   partials = (int*)  alloc(((size_t)(N + 255) / 256) * 4);
    int*   csr_src  = (int*)  alloc((size_t)E * 4);
    float* hps      = (float*)alloc((size_t)N * 32 * 4);
    float* catb     = (float*)alloc((size_t)N * 96 * 4);
    int*   idx      = (int*)  alloc((size_t)G * 4);

    const int nb  = (N + 255) / 256;   // scan blocks
    const int ebl = (E + 255) / 256;
    const int nodes_bl = (N * 32 + 255) / 256;   // 8 nodes per block
    const int gemm_bl  = (N + 7) / 8;

    hipMemsetAsync(cnt, 0, (size_t)N * 4, stream);

    k_count<<<ebl, 256, 0, stream>>>(dst, cnt, E);
    k_dis<<<nb, 256, 0, stream>>>(cnt, dis, N);
    k_scan1<<<nb, 256, 0, stream>>>(cnt, rowptr, partials, N);
    k_scan2<<<1, 512, 0, stream>>>(partials, nb);
    k_scan3<<<nb, 256, 0, stream>>>(rowptr, partials, N);
    hipMemcpyAsync(cursor, rowptr, (size_t)N * 4, hipMemcpyDeviceToDevice, stream);
    k_fill<<<ebl, 256, 0, stream>>>(src, dst, cursor, csr_src, E);

    // layer 1: x[N,128] @ W1 -> hps ; aggregate -> catb[:,0:32]
    k_gemm<128><<<gemm_bl, 256, 0, stream>>>(x, 128, W1, dis, hps, N);
    k_agg<<<nodes_bl, 256, 0, stream>>>(hps, rowptr, csr_src, dis, b1, catb + 0, 96, N);
    // layer 2: catb[:,0:32] @ W2 -> hps ; aggregate -> catb[:,32:64]
    k_gemm<32><<<gemm_bl, 256, 0, stream>>>(catb + 0, 96, W2, dis, hps, N);
    k_agg<<<nodes_bl, 256, 0, stream>>>(hps, rowptr, csr_src, dis, b2, catb + 32, 96, N);
    // layer 3: catb[:,32:64] @ W3 -> hps ; aggregate -> catb[:,64:96]
    k_gemm<32><<<gemm_bl, 256, 0, stream>>>(catb + 32, 96, W3, dis, hps, N);
    k_agg<<<nodes_bl, 256, 0, stream>>>(hps, rowptr, csr_src, dis, b3, catb + 64, 96, N);

    k_idx<<<(G + 255) / 256, 256, 0, stream>>>(batch, idx, N, G);
    k_head<<<G, 128, 0, stream>>>(catb, idx, l1w, l1b, l2w, l2b, out);
}

// Round 3
// 441.097 us; speedup vs baseline: 1.2627x; 1.1352x over previous
//
#include <hip/hip_runtime.h>
#include <math.h>

// ---------------------------------------------------------------------------
// GCN: 3 layers (128->32->32->32), CSR-by-dst aggregation, readout + MLP head
// Algebra: agg[g] = tanh( dis[g] * ( sum_{e:dst=g} hps[src_e] + hps[g] ) + b )
//          where hps = dis ⊙ (h @ W)   (so no per-edge coef storage needed)
// CSR build is dst-bucketed by blockIdx&7 (~XCD id): all stores to a given
// dst row come from one XCD's L2 -> full-line writebacks, no amplification.
// ---------------------------------------------------------------------------

__global__ void k_count(const int* __restrict__ dst, int* __restrict__ cnt,
                        int E, int N) {
    int q  = blockIdx.x & 7;
    int r  = blockIdx.x >> 3;
    int nb = gridDim.x >> 3;
    int lo = (int)(((long long)q * N) / 8);
    int hi = (int)(((long long)(q + 1) * N) / 8);
    for (int e = r * blockDim.x + threadIdx.x; e < E; e += nb * blockDim.x) {
        int d = dst[e];
        if (d >= lo && d < hi) atomicAdd(&cnt[d], 1);
    }
}

__global__ void k_dis(const int* __restrict__ cnt, float* __restrict__ dis, int n) {
    int i = blockIdx.x * blockDim.x + threadIdx.x;
    if (i < n) {
        float d = 1.0f + (float)cnt[i];
        dis[i] = 1.0f / sqrtf(d);
    }
}

// inclusive block scan of cnt -> rowptr[i+1] (without inter-block offsets), partials[b]=block sum
__global__ void k_scan1(const int* __restrict__ cnt, int* __restrict__ rowptr,
                        int* __restrict__ partials, int n) {
    __shared__ int s[256];
    int i = blockIdx.x * 256 + threadIdx.x;
    int v = (i < n) ? cnt[i] : 0;
    s[threadIdx.x] = v;
    __syncthreads();
    for (int off = 1; off < 256; off <<= 1) {
        int t = (threadIdx.x >= off) ? s[threadIdx.x - off] : 0;
        __syncthreads();
        s[threadIdx.x] += t;
        __syncthreads();
    }
    if (i < n) rowptr[i + 1] = s[threadIdx.x];
    if (threadIdx.x == 255) partials[blockIdx.x] = s[255];
}

// exclusive scan of partials (nb <= 512), single block
__global__ void k_scan2(int* __restrict__ partials, int nb) {
    __shared__ int s[512];
    int t = threadIdx.x;
    s[t] = (t < nb) ? partials[t] : 0;
    __syncthreads();
    for (int off = 1; off < 512; off <<= 1) {
        int v = (t >= off) ? s[t - off] : 0;
        __syncthreads();
        s[t] += v;
        __syncthreads();
    }
    if (t < nb) partials[t] = (t == 0) ? 0 : s[t - 1];
}

__global__ void k_scan3(int* __restrict__ rowptr, const int* __restrict__ partials, int n) {
    int i = blockIdx.x * 256 + threadIdx.x;
    if (i < n) rowptr[i + 1] += partials[blockIdx.x];
    if (i == 0) rowptr[0] = 0;
}

// cursor pre-initialized to rowptr; dst-bucketed so each CSR line is written
// from a single XCD's L2 (full-line writebacks).
__global__ void k_fill(const int* __restrict__ src, const int* __restrict__ dst,
                       int* __restrict__ cursor, int* __restrict__ csr_src,
                       int E, int N) {
    int q  = blockIdx.x & 7;
    int r  = blockIdx.x >> 3;
    int nb = gridDim.x >> 3;
    int lo = (int)(((long long)q * N) / 8);
    int hi = (int)(((long long)(q + 1) * N) / 8);
    for (int e = r * blockDim.x + threadIdx.x; e < E; e += nb * blockDim.x) {
        int d = dst[e];
        if (d >= lo && d < hi) {
            int pos = atomicAdd(&cursor[d], 1);
            csr_src[pos] = src[e];
        }
    }
}

// hps[n,32] = dis[row] * ( h[n, first K cols of ldh] @ W[K,32] )
template <int K>
__global__ void k_gemm(const float* __restrict__ h, int ldh, const float* __restrict__ W,
                       const float* __restrict__ dis, float* __restrict__ hps, int n) {
    __shared__ float sW[K * 32];
    __shared__ float sh[8][K + 1];
    int tid = threadIdx.x;
    for (int i = tid; i < K * 32; i += 256) sW[i] = W[i];
    int row0 = blockIdx.x * 8;
    for (int idx = tid; idx < 8 * K; idx += 256) {
        int r = idx / K, c = idx % K;
        sh[r][c] = (row0 + r < n) ? h[(size_t)(row0 + r) * ldh + c] : 0.0f;
    }
    __syncthreads();
    int r = tid >> 5, col = tid & 31;
    float acc = 0.0f;
#pragma unroll 8
    for (int k = 0; k < K; ++k) acc += sh[r][k] * sW[k * 32 + col];
    int row = row0 + r;
    if (row < n) hps[(size_t)row * 32 + col] = acc * dis[row];
}

// out[node, col+offset] = tanh( dis[g] * (sum_in-edges hps[src] + hps[g]) + b )
__global__ void k_agg(const float* __restrict__ hps, const int* __restrict__ rowptr,
                      const int* __restrict__ csr_src, const float* __restrict__ dis,
                      const float* __restrict__ bias, float* __restrict__ out,
                      int ldo, int n) {
    int g    = (blockIdx.x * blockDim.x + threadIdx.x) >> 5;
    int lane = threadIdx.x & 31;
    if (g >= n) return;
    float acc = hps[(size_t)g * 32 + lane];   // self term (dis[g]^2 * h' = dis*hps)
    int e0 = rowptr[g], e1 = rowptr[g + 1];
    int e = e0;
    for (; e + 1 < e1; e += 2) {
        int s0 = csr_src[e];
        int s1 = csr_src[e + 1];
        float v0 = hps[(size_t)s0 * 32 + lane];
        float v1 = hps[(size_t)s1 * 32 + lane];
        acc += v0 + v1;
    }
    if (e < e1) acc += hps[(size_t)csr_src[e] * 32 + lane];
    float v = dis[g] * acc + bias[lane];
    out[(size_t)g * ldo + lane] = tanhf(v);
}

__global__ void k_idx(const int* __restrict__ batch, int* __restrict__ idx, int n, int g) {
    int i = blockIdx.x * blockDim.x + threadIdx.x;
    if (i >= g) return;
    int lo = 0, hi = n;
    while (lo < hi) {
        int mid = (lo + hi) >> 1;
        if (batch[mid] < i) lo = mid + 1; else hi = mid;
    }
    idx[i] = lo;
}

// per graph: gv[96] -> hidden[128] (relu) -> logits[2] -> log_softmax
__global__ void k_head(const float* __restrict__ cat, const int* __restrict__ idx,
                       const float* __restrict__ w1, const float* __restrict__ b1,
                       const float* __restrict__ w2, const float* __restrict__ b2,
                       float* __restrict__ out) {
    __shared__ float gv[96];
    __shared__ float s0[128];
    __shared__ float s1[128];
    int g = blockIdx.x, t = threadIdx.x;
    int node = idx[g];
    if (t < 96) gv[t] = cat[(size_t)node * 96 + t];
    __syncthreads();
    float acc = b1[t];
#pragma unroll 8
    for (int i = 0; i < 96; ++i) acc += gv[i] * w1[i * 128 + t];
    float h = fmaxf(acc, 0.0f);
    s0[t] = h * w2[t * 2 + 0];
    s1[t] = h * w2[t * 2 + 1];
    __syncthreads();
    for (int off = 64; off > 0; off >>= 1) {
        if (t < off) { s0[t] += s0[t + off]; s1[t] += s1[t + off]; }
        __syncthreads();
    }
    if (t == 0) {
        float l0 = s0[0] + b2[0];
        float l1 = s1[0] + b2[1];
        float m  = fmaxf(l0, l1);
        float lse = m + logf(expf(l0 - m) + expf(l1 - m));
        out[(size_t)g * 2 + 0] = l0 - lse;
        out[(size_t)g * 2 + 1] = l1 - lse;
    }
}

extern "C" void kernel_launch(void* const* d_in, const int* in_sizes, int n_in,
                              void* d_out, int out_size, void* d_ws, size_t ws_size,
                              hipStream_t stream) {
    const float* x    = (const float*)d_in[0];
    const int*   ei   = (const int*)d_in[1];
    const int*   batch= (const int*)d_in[2];
    const float* W1   = (const float*)d_in[4];
    const float* b1   = (const float*)d_in[5];
    const float* W2   = (const float*)d_in[6];
    const float* b2   = (const float*)d_in[7];
    const float* W3   = (const float*)d_in[8];
    const float* b3   = (const float*)d_in[9];
    const float* l1w  = (const float*)d_in[10];
    const float* l1b  = (const float*)d_in[11];
    const float* l2w  = (const float*)d_in[12];
    const float* l2b  = (const float*)d_in[13];
    float* out = (float*)d_out;

    const int N = in_sizes[0] / 128;
    const int E = in_sizes[1] / 2;
    const int G = out_size / 2;
    const int* src = ei;
    const int* dst = ei + E;

    char* w = (char*)d_ws;
    auto alloc = [&](size_t bytes) {
        char* p = w;
        w += (bytes + 255) & ~(size_t)255;
        return p;
    };
    int*   cnt      = (int*)  alloc((size_t)N * 4);
    float* dis      = (float*)alloc((size_t)N * 4);
    int*   rowptr   = (int*)  alloc((size_t)(N + 1) * 4);
    int*   cursor   = (int*)  alloc((size_t)N * 4);
    int*   partials = (int*)  alloc(((size_t)(N + 255) / 256) * 4);
    int*   csr_src  = (int*)  alloc((size_t)E * 4);
    float* hps      = (float*)alloc((size_t)N * 32 * 4);
    float* catb     = (float*)alloc((size_t)N * 96 * 4);
    int*   idx      = (int*)  alloc((size_t)G * 4);

    const int nb  = (N + 255) / 256;   // scan blocks
    const int nodes_bl = (N * 32 + 255) / 256;   // 8 nodes per block
    const int gemm_bl  = (N + 7) / 8;
    const int bkt_bl   = 2048;          // bucketed edge kernels: 256 blocks/bucket

    hipMemsetAsync(cnt, 0, (size_t)N * 4, stream);

    k_count<<<bkt_bl, 256, 0, stream>>>(dst, cnt, E, N);
    k_dis<<<nb, 256, 0, stream>>>(cnt, dis, N);
    k_scan1<<<nb, 256, 0, stream>>>(cnt, rowptr, partials, N);
    k_scan2<<<1, 512, 0, stream>>>(partials, nb);
    k_scan3<<<nb, 256, 0, stream>>>(rowptr, partials, N);
    hipMemcpyAsync(cursor, rowptr, (size_t)N * 4, hipMemcpyDeviceToDevice, stream);
    k_fill<<<bkt_bl, 256, 0, stream>>>(src, dst, cursor, csr_src, E, N);

    // layer 1: x[N,128] @ W1 -> hps ; aggregate -> catb[:,0:32]
    k_gemm<128><<<gemm_bl, 256, 0, stream>>>(x, 128, W1, dis, hps, N);
    k_agg<<<nodes_bl, 256, 0, stream>>>(hps, rowptr, csr_src, dis, b1, catb + 0, 96, N);
    // layer 2: catb[:,0:32] @ W2 -> hps ; aggregate -> catb[:,32:64]
    k_gemm<32><<<gemm_bl, 256, 0, stream>>>(catb + 0, 96, W2, dis, hps, N);
    k_agg<<<nodes_bl, 256, 0, stream>>>(hps, rowptr, csr_src, dis, b2, catb + 32, 96, N);
    // layer 3: catb[:,32:64] @ W3 -> hps ; aggregate -> catb[:,64:96]
    k_gemm<32><<<gemm_bl, 256, 0, stream>>>(catb + 32, 96, W3, dis, hps, N);
    k_agg<<<nodes_bl, 256, 0, stream>>>(hps, rowptr, csr_src, dis, b3, catb + 64, 96, N);

    k_idx<<<(G + 255) / 256, 256, 0, stream>>>(batch, idx, N, G);
    k_head<<<G, 128, 0, stream>>>(catb, idx, l1w, l1b, l2w, l2b, out);
}